// Round 1
// baseline (579.127 us; speedup 1.0000x reference)
//
#include <hip/hip_runtime.h>
#include <hip/hip_bf16.h>

// FactorAtt (CoaT) fused pipeline, MI355X/gfx950.
// B=8, N=4096, C=768, H=12, D=64.  M_tot = B*N = 32768.
//
// Math: out[b] = Qh[b] @ G[b] + bp, where
//   Qh = q @ Wq^T (bf16), Kh = k @ Wk^T, Vh = v @ Wv^T
//   ctx[b,h,dk,dv] = sum_n softmax_n(Kh)[n,dk] * Vh[n,dv]
//   G[b][h*64+dk][co] = sum_dv ctx[b,h,dk,dv] * Wp[co, h*64+dv]
// (head-transpose + factor_att + out-proj fused algebraically into one GEMM)

typedef __bf16 bf16x8 __attribute__((ext_vector_type(8)));
typedef float f32x4 __attribute__((ext_vector_type(4)));
typedef unsigned short u16x4 __attribute__((ext_vector_type(4)));

#define GLOAD_LDS16(g, l)                                                        \
  __builtin_amdgcn_global_load_lds(                                              \
      (const __attribute__((address_space(1))) void*)(g),                        \
      (__attribute__((address_space(3))) void*)(l), 16, 0, 0)

__device__ __forceinline__ unsigned short f2bf(float x) {
  __hip_bfloat16 h = __float2bfloat16(x);
  unsigned short u;
  __builtin_memcpy(&u, &h, 2);
  return u;
}
__device__ __forceinline__ float bf2f(__hip_bfloat16 h) { return __bfloat162float(h); }

// ---------------------------------------------------------------- cast fp32->bf16
__global__ void cast_kernel(const float* __restrict__ src,
                            __hip_bfloat16* __restrict__ dst, long n) {
  long i = ((long)blockIdx.x * blockDim.x + threadIdx.x) * 4;
  if (i + 3 < n) {
    const float4 f = *(const float4*)(src + i);
    u16x4 u = {f2bf(f.x), f2bf(f.y), f2bf(f.z), f2bf(f.w)};
    *(u16x4*)(dst + i) = u;  // 8B store
  }
}

// ---------------------------------------------------------------- GEMM (B^T form)
// out[m,n] = sum_k A[m,k] * Bt[n,k];  M=32768 (tiles of 128), N=768, K=768.
// m97 structure: 128x128 tile, BK=32, 4 waves (2x2 of 64x64), global_load_lds.
// z-batched: A += z*sAz, Bt += z*sBz, outB += z*sOz.
// Final mode (outF != nullptr): Bt additionally batched per 4096 rows (sBbatch),
// fp32 output with bias.
__global__ __launch_bounds__(256, 2)
void gemm_bt(const __hip_bfloat16* __restrict__ Abase,
             const __hip_bfloat16* __restrict__ Btbase,
             __hip_bfloat16* __restrict__ outBbase,
             float* __restrict__ outF,
             const float* __restrict__ bias,
             long sAz, long sBz, long sOz, long sBbatch) {
  constexpr int K = 768;
  const int tid = threadIdx.x;
  const int lane = tid & 63;
  const int w = tid >> 6;
  const int wr = (w >> 1) * 64;  // wave row offset in tile
  const int wc = (w & 1) * 64;   // wave col offset in tile
  const int z = blockIdx.z;
  const int m0 = blockIdx.y * 128;
  const int n0 = blockIdx.x * 128;

  const __hip_bfloat16* A = Abase + (long)z * sAz;
  const __hip_bfloat16* Bt = Btbase + (long)z * sBz + (long)(m0 >> 12) * sBbatch;

  __shared__ __align__(16) __hip_bfloat16 As[128 * 32];
  __shared__ __align__(16) __hip_bfloat16 Bs[128 * 32];

  f32x4 acc[4][4] = {};

  // staging: each thread moves 16B; wave w covers rows w*16 .. w*16+15 (per half)
  // LDS dest must be wave-uniform base + lane*16 (global_load_lds constraint).
  const int srow = w * 16 + (lane >> 2);
  const int scol = (lane & 3) * 8;
  const __hip_bfloat16* gA = A + (long)(m0 + srow) * K + scol;
  const __hip_bfloat16* gB = Bt + (long)(n0 + srow) * K + scol;
  __hip_bfloat16* lA = &As[(w * 16) * 32];
  __hip_bfloat16* lB = &Bs[(w * 16) * 32];

  const int kseg = (lane >> 4) * 8;  // A/B frag: k = (lane>>4)*8 + j
  const int rsel = lane & 15;        // A frag row / B frag col

  for (int k0 = 0; k0 < K; k0 += 32) {
    GLOAD_LDS16(gA + k0, lA);
    GLOAD_LDS16(gA + (long)64 * K + k0, lA + 64 * 32);
    GLOAD_LDS16(gB + k0, lB);
    GLOAD_LDS16(gB + (long)64 * K + k0, lB + 64 * 32);
    __syncthreads();  // compiler emits vmcnt(0) drain before barrier

    bf16x8 af[4], bfr[4];
#pragma unroll
    for (int i = 0; i < 4; ++i) {
      af[i] = *(const bf16x8*)&As[(wr + i * 16 + rsel) * 32 + kseg];
      bfr[i] = *(const bf16x8*)&Bs[(wc + i * 16 + rsel) * 32 + kseg];
    }
#pragma unroll
    for (int i = 0; i < 4; ++i)
#pragma unroll
      for (int j = 0; j < 4; ++j)
        acc[i][j] = __builtin_amdgcn_mfma_f32_16x16x32_bf16(af[i], bfr[j], acc[i][j], 0, 0, 0);
    __syncthreads();
  }

  // C/D layout (m89-verified): col = lane&15, row = (lane>>4)*4 + r
  const int r0 = (lane >> 4) * 4;
  if (outF == nullptr) {
    __hip_bfloat16* outp = outBbase + (long)z * sOz;
#pragma unroll
    for (int i = 0; i < 4; ++i) {
      const int row = m0 + wr + i * 16 + r0;
#pragma unroll
      for (int j = 0; j < 4; ++j) {
        const int col = n0 + wc + j * 16 + rsel;
#pragma unroll
        for (int r = 0; r < 4; ++r)
          outp[(long)(row + r) * 768 + col] = __float2bfloat16(acc[i][j][r]);
      }
    }
  } else {
#pragma unroll
    for (int i = 0; i < 4; ++i) {
      const int row = m0 + wr + i * 16 + r0;
#pragma unroll
      for (int j = 0; j < 4; ++j) {
        const int col = n0 + wc + j * 16 + rsel;
        const float bv = bias[col];
#pragma unroll
        for (int r = 0; r < 4; ++r)
          outF[(long)(row + r) * 768 + col] = acc[i][j][r] + bv;
      }
    }
  }
}

// ---------------------------------------------------------------- ctx partials
// Per (b,h) and n-chunk of 512: U[dk,dv] += exp(Kh[n,dk]) * Vh[n,dv];
// S[dk] += exp(Kh[n,dk]).  No max-subtraction: kh ~ N(0,1), |kh|max ~ 5.6,
// exp <= ~300, fp32 sums safe; mathematically identical to ref softmax.
__global__ __launch_bounds__(256)
void ctx_partial(const __hip_bfloat16* __restrict__ Kh,
                 const __hip_bfloat16* __restrict__ Vh,
                 float* __restrict__ Upart, float* __restrict__ Spart) {
  const int bh = blockIdx.y, chunk = blockIdx.x;
  const int b = bh / 12, h = bh % 12;
  const int t = threadIdx.x;
  const int rr = t >> 6, d = t & 63;            // loader role: row-group, column
  const int tdk = (t & 15) * 4, tdv = (t >> 4) * 4;  // accumulator role: 4x4 cell
  __shared__ float ek[4][64];
  __shared__ float vv[4][64];
  __shared__ float sred[256];
  f32x4 U[4] = {};  // U[i] = row tdk+i, cols tdv..tdv+3
  float myS = 0.f;
  const long base = ((long)b * 4096 + (long)chunk * 512) * 768 + h * 64 + d;
  for (int r4 = 0; r4 < 128; ++r4) {
    const long off = base + (long)(r4 * 4 + rr) * 768;
    const float e = __expf(bf2f(Kh[off]));
    ek[rr][d] = e;
    myS += e;
    vv[rr][d] = bf2f(Vh[off]);
    __syncthreads();
#pragma unroll
    for (int q = 0; q < 4; ++q) {
      const f32x4 a = *(const f32x4*)&ek[q][tdk];
      const f32x4 vx = *(const f32x4*)&vv[q][tdv];
      U[0] += a[0] * vx;
      U[1] += a[1] * vx;
      U[2] += a[2] * vx;
      U[3] += a[3] * vx;
    }
    __syncthreads();
  }
  float* Ub = Upart + (long)(bh * 8 + chunk) * 4096;
#pragma unroll
  for (int i = 0; i < 4; ++i) *(f32x4*)&Ub[(tdk + i) * 64 + tdv] = U[i];
  sred[t] = myS;
  __syncthreads();
  if (t < 64) {
    const float s = sred[t] + sred[t + 64] + sred[t + 128] + sred[t + 192];
    Spart[(long)(bh * 8 + chunk) * 64 + t] = s;  // column sum for this chunk
  }
}

__global__ __launch_bounds__(256)
void ctx_reduce(const float* __restrict__ Upart, const float* __restrict__ Spart,
                float* __restrict__ ctx) {
  const int bh = blockIdx.x;
  const int t = threadIdx.x;
  const int tdk = (t & 15) * 4, tdv = (t >> 4) * 4;
  __shared__ float S[64];
  if (t < 64) {
    float s = 0.f;
#pragma unroll
    for (int c = 0; c < 8; ++c) s += Spart[(long)(bh * 8 + c) * 64 + t];
    S[t] = s;
  }
  __syncthreads();
#pragma unroll
  for (int i = 0; i < 4; ++i) {
    const int dk = tdk + i;
    f32x4 u = {};
#pragma unroll
    for (int c = 0; c < 8; ++c)
      u += *(const f32x4*)&Upart[(long)(bh * 8 + c) * 4096 + dk * 64 + tdv];
    u *= (1.f / S[dk]);
    *(f32x4*)&ctx[(long)bh * 4096 + dk * 64 + tdv] = u;
  }
}

// ---------------------------------------------------------------- G matrix
// Gt[b][co][h*64+dk] = sum_dv ctx[b,h,dk,dv] * Wp[co, h*64+dv]   (bf16 out)
__global__ void gstack(const float* __restrict__ ctx,
                       const __hip_bfloat16* __restrict__ Wpb,
                       __hip_bfloat16* __restrict__ Gt) {
  const int co = blockIdx.x, b = blockIdx.y, l = threadIdx.x;  // l = dk
  for (int h = 0; h < 12; ++h) {
    const float* crow = ctx + ((long)(b * 12 + h) * 64 + l) * 64;
    const __hip_bfloat16* wrow = Wpb + (long)co * 768 + h * 64;
    float sum = 0.f;
    for (int dv = 0; dv < 64; dv += 4) {
      const f32x4 c4 = *(const f32x4*)&crow[dv];
      sum += c4[0] * bf2f(wrow[dv]) + c4[1] * bf2f(wrow[dv + 1]) +
             c4[2] * bf2f(wrow[dv + 2]) + c4[3] * bf2f(wrow[dv + 3]);
    }
    Gt[((long)b * 768 + co) * 768 + h * 64 + l] = __float2bfloat16(sum);
  }
}

// ---------------------------------------------------------------- launch
extern "C" void kernel_launch(void* const* d_in, const int* in_sizes, int n_in,
                              void* d_out, int out_size, void* d_ws, size_t ws_size,
                              hipStream_t stream) {
  (void)in_sizes; (void)n_in; (void)out_size; (void)ws_size;
  const float* q = (const float*)d_in[0];
  const float* k = (const float*)d_in[1];
  const float* v = (const float*)d_in[2];
  const float* Wq = (const float*)d_in[3];
  const float* Wk = (const float*)d_in[4];
  const float* Wv = (const float*)d_in[5];
  const float* Wp = (const float*)d_in[6];
  const float* bp = (const float*)d_in[7];
  float* out = (float*)d_out;

  const long XE = 32768L * 768L;  // 25,165,824 elements (one activation matrix)
  const long WE = 768L * 768L;    // 589,824

  // ws layout (peak ~293 MB):
  //   [Xb: 3*XE bf16][Wb: 4*WE bf16][Hb: 3*XE bf16]
  // Xb region is reused (dead after projections) for Upart/Spart/ctx/Gt.
  char* ws = (char*)d_ws;
  __hip_bfloat16* Xb = (__hip_bfloat16*)ws;
  __hip_bfloat16* Wb = Xb + 3 * XE;
  __hip_bfloat16* Hb = Wb + 4 * WE;
  float* Upart = (float*)ws;                 // 96*8*64*64 f32 = 12.6 MB
  float* Spart = Upart + 96L * 8 * 64 * 64;  // 96*8*64 f32
  float* ctx = Spart + 96L * 8 * 64;         // 96*64*64 f32
  __hip_bfloat16* Gt = (__hip_bfloat16*)(ctx + 96L * 64 * 64);  // 8*768*768 bf16

  // 1) casts to bf16
  cast_kernel<<<24576, 256, 0, stream>>>(q, Xb + 0 * XE, XE);
  cast_kernel<<<24576, 256, 0, stream>>>(k, Xb + 1 * XE, XE);
  cast_kernel<<<24576, 256, 0, stream>>>(v, Xb + 2 * XE, XE);
  cast_kernel<<<576, 256, 0, stream>>>(Wq, Wb + 0 * WE, WE);
  cast_kernel<<<576, 256, 0, stream>>>(Wk, Wb + 1 * WE, WE);
  cast_kernel<<<576, 256, 0, stream>>>(Wv, Wb + 2 * WE, WE);
  cast_kernel<<<576, 256, 0, stream>>>(Wp, Wb + 3 * WE, WE);

  // 2) Q/K/V projections (z-batched): Hb[z] = Xb[z] @ Wb[z]^T  (bf16 out)
  gemm_bt<<<dim3(6, 256, 3), 256, 0, stream>>>(Xb, Wb, Hb, nullptr, nullptr,
                                               XE, WE, XE, 0);

  // 3) softmax-weighted context
  ctx_partial<<<dim3(8, 96), 256, 0, stream>>>(Hb + XE, Hb + 2 * XE, Upart, Spart);
  ctx_reduce<<<96, 256, 0, stream>>>(Upart, Spart, ctx);

  // 4) per-batch fused B-matrix G
  gstack<<<dim3(768, 8), 64, 0, stream>>>(ctx, Wb + 3 * WE, Gt);

  // 5) out[b] = Qh[b] @ G[b] + bp  (fp32 out, batched Bt per 4096 rows)
  gemm_bt<<<dim3(6, 256, 1), 256, 0, stream>>>(Hb, Gt, nullptr, out, bp,
                                               0, 0, 0, WE);
}

// Round 3
// 508.466 us; speedup vs baseline: 1.1390x; 1.1390x over previous
//
#include <hip/hip_runtime.h>
#include <hip/hip_bf16.h>

// FactorAtt (CoaT) fused pipeline v2, MI355X/gfx950.
// B=8, N=4096, C=768, H=12, D=64.  M_tot = B*N = 32768.
//
// Math: out[b] = q[b] @ M[b] + bp, where
//   Kh = k @ Wk^T (bf16), Vh = v @ Wv^T
//   ctx[b,h,dk,dv] = sum_n softmax_n(Kh)[n,dk] * Vh[n,dv]
//   Gt[b][co][h*64+dk] = sum_dv ctx[b,h,dk,dv] * Wp[co, h*64+dv]
//   Mt[b][co][ci] = sum_kk Gt[b][co][kk] * Wq[kk][ci]      (= (Wq^T G)^T)
//   out[b][n,co] = sum_ci q[b][n,ci] * Mt[b][co,ci] + bp[co]
// Qh projection and output projection both folded into M (tiny per-batch GEMMs).
// fp32->bf16 casts of activations fused into the GEMM A-staging path.

typedef __bf16 bf16x8 __attribute__((ext_vector_type(8)));
typedef __bf16 bf16x4 __attribute__((ext_vector_type(4)));
typedef float f32x4 __attribute__((ext_vector_type(4)));

#define GLOAD_LDS16(g, l)                                                        \
  __builtin_amdgcn_global_load_lds(                                              \
      (const __attribute__((address_space(1))) void*)(g),                        \
      (__attribute__((address_space(3))) void*)(l), 16, 0, 0)

__device__ __forceinline__ float bf2f(__hip_bfloat16 h) { return __bfloat162float(h); }

// ---------------------------------------------------------------- cast fp32->bf16
__global__ void cast_kernel(const float* __restrict__ src,
                            __bf16* __restrict__ dst, long n) {
  long i = ((long)blockIdx.x * blockDim.x + threadIdx.x) * 4;
  if (i + 3 < n) {
    const float4 f = *(const float4*)(src + i);
    bf16x4 u = {(__bf16)f.x, (__bf16)f.y, (__bf16)f.z, (__bf16)f.w};
    *(bf16x4*)(dst + i) = u;
  }
}

// ---------------------------------------------------------------- transpose cast
// dst[ci][kk] = src[kk][ci]  (768x768, fp32 -> bf16)
__global__ void transpose_cast(const float* __restrict__ src,
                               __bf16* __restrict__ dst) {
  __shared__ float tile[32][33];
  const int bx = blockIdx.x * 32, by = blockIdx.y * 32;  // bx: kk base, by: ci base
  const int tx = threadIdx.x, ty = threadIdx.y;          // 32 x 8
#pragma unroll
  for (int j = 0; j < 32; j += 8)
    tile[ty + j][tx] = src[(long)(bx + ty + j) * 768 + by + tx];
  __syncthreads();
#pragma unroll
  for (int j = 0; j < 32; j += 8)
    dst[(long)(by + ty + j) * 768 + bx + tx] = (__bf16)tile[tx][ty + j];
}

// ---------------------------------------------------------------- GEMM (B^T form)
// out[m,n] = sum_k A[m,k] * Bt[n,k];  K=768 fixed, tiles 128x128, BK=32, 4 waves.
// AF32: A is fp32 in global, cast to bf16 at LDS->frag read (XOR-swizzled LDS).
// z-batched: A += z*sAz, Bt += z*sBz, outB += z*sOz.  If outF: fp32 out + bias,
// Bt additionally batched per 4096 rows (sBbatch).
template <bool AF32>
__global__ __launch_bounds__(256, 2)
void gemm_bt(const void* __restrict__ Abase_,
             const __bf16* __restrict__ Btbase,
             __bf16* __restrict__ outBbase,
             float* __restrict__ outF,
             const float* __restrict__ bias,
             long sAz, long sBz, long sOz, long sBbatch) {
  constexpr int K = 768;
  const int tid = threadIdx.x;
  const int lane = tid & 63;
  const int w = tid >> 6;
  const int wr = (w >> 1) * 64;
  const int wc = (w & 1) * 64;

  // bijective XCD-chunked swizzle (m204): each XCD gets a contiguous logical range
  long flat = ((long)blockIdx.z * gridDim.y + blockIdx.y) * gridDim.x + blockIdx.x;
  const long total = (long)gridDim.x * gridDim.y * gridDim.z;
  if ((total & 7) == 0) {
    flat = (flat & 7) * (total >> 3) + (flat >> 3);
  }
  const int bx = (int)(flat % gridDim.x);
  const long rem = flat / gridDim.x;
  const int by = (int)(rem % gridDim.y);
  const int bz = (int)(rem / gridDim.y);

  const int z = bz;
  const int m0 = by * 128;
  const int n0 = bx * 128;

  const __bf16* Bt = Btbase + (long)z * sBz + (long)(m0 >> 12) * sBbatch;

  __shared__ __align__(16) float AsF[AF32 ? 128 * 32 : 8];
  __shared__ __align__(16) __bf16 AsB[AF32 ? 8 : 128 * 32];
  __shared__ __align__(16) __bf16 Bs[128 * 32];

  f32x4 acc[4][4] = {};

  // ---- staging setup
  // B (bf16): wave w covers rows w*16..+15 (and +64); lane: row = lane>>2, chunk = lane&3
  const int srow = w * 16 + (lane >> 2);
  const int scol = (lane & 3) * 8;
  const __bf16* gB = Bt + (long)(n0 + srow) * K + scol;
  __bf16* lB = &Bs[(w * 16) * 32];

  // A fp32: per issue p (0..3), rows p*32 + w*8 + (lane>>3), chunk lane&7 (16B units)
  // XOR swizzle: physical chunk c holds logical chunk c ^ (row&7)
  const int sr8 = lane >> 3;              // row within 8-row group == row&7
  const int c_log = (lane & 7) ^ sr8;     // logical 16B-chunk to fetch
  const float* gAf = nullptr;
  float* lAf = nullptr;
  const __bf16* gAb = nullptr;
  __bf16* lAb = nullptr;
  if (AF32) {
    const float* Af = (const float*)Abase_ + (long)z * sAz;
    gAf = Af + (long)(m0 + w * 8 + sr8) * K + c_log * 4;
    lAf = &AsF[(w * 8) * 32];
  } else {
    const __bf16* Ab = (const __bf16*)Abase_ + (long)z * sAz;
    gAb = Ab + (long)(m0 + srow) * K + scol;
    lAb = &AsB[(w * 16) * 32];
  }

  const int kseg = (lane >> 4) * 8;  // frag k-offset (elements)
  const int rsel = lane & 15;
  const int r7 = rsel & 7;           // (frag row)&7 for A-swizzle readback

  for (int k0 = 0; k0 < K; k0 += 32) {
    if (AF32) {
#pragma unroll
      for (int p = 0; p < 4; ++p)
        GLOAD_LDS16(gAf + k0 + (long)p * 32 * K, lAf + p * 32 * 32);
    } else {
      GLOAD_LDS16(gAb + k0, lAb);
      GLOAD_LDS16(gAb + (long)64 * K + k0, lAb + 64 * 32);
    }
    GLOAD_LDS16(gB + k0, lB);
    GLOAD_LDS16(gB + (long)64 * K + k0, lB + 64 * 32);
    __syncthreads();

    bf16x8 af[4], bfr[4];
#pragma unroll
    for (int i = 0; i < 4; ++i) {
      const int row = wr + i * 16 + rsel;
      if (AF32) {
        const int c0 = kseg >> 2;  // logical 16B chunk (even)
        const f32x4 lo = *(const f32x4*)&AsF[row * 32 + ((c0 ^ r7) << 2)];
        const f32x4 hi = *(const f32x4*)&AsF[row * 32 + (((c0 + 1) ^ r7) << 2)];
        bf16x8 a = {(__bf16)lo[0], (__bf16)lo[1], (__bf16)lo[2], (__bf16)lo[3],
                    (__bf16)hi[0], (__bf16)hi[1], (__bf16)hi[2], (__bf16)hi[3]};
        af[i] = a;
      } else {
        af[i] = *(const bf16x8*)&AsB[row * 32 + kseg];
      }
      bfr[i] = *(const bf16x8*)&Bs[(wc + i * 16 + rsel) * 32 + kseg];
    }
#pragma unroll
    for (int i = 0; i < 4; ++i)
#pragma unroll
      for (int j = 0; j < 4; ++j)
        acc[i][j] = __builtin_amdgcn_mfma_f32_16x16x32_bf16(af[i], bfr[j], acc[i][j], 0, 0, 0);
    __syncthreads();
  }

  // C/D layout (m89): col = lane&15, row = (lane>>4)*4 + r
  const int r0 = (lane >> 4) * 4;
  if (outF == nullptr) {
    __bf16* outp = outBbase + (long)z * sOz;
#pragma unroll
    for (int i = 0; i < 4; ++i) {
      const int row = m0 + wr + i * 16 + r0;
#pragma unroll
      for (int j = 0; j < 4; ++j) {
        const int col = n0 + wc + j * 16 + rsel;
#pragma unroll
        for (int r = 0; r < 4; ++r)
          outp[(long)(row + r) * 768 + col] = (__bf16)acc[i][j][r];
      }
    }
  } else {
#pragma unroll
    for (int i = 0; i < 4; ++i) {
      const int row = m0 + wr + i * 16 + r0;
#pragma unroll
      for (int j = 0; j < 4; ++j) {
        const int col = n0 + wc + j * 16 + rsel;
        const float bv = bias[col];
#pragma unroll
        for (int r = 0; r < 4; ++r)
          outF[(long)(row + r) * 768 + col] = acc[i][j][r] + bv;
      }
    }
  }
}

// ---------------------------------------------------------------- ctx partials
// Per (b,h) and n-chunk of 512: U[dk,dv] += exp(Kh[n,dk]) * Vh[n,dv];
// S[dk] += exp(Kh[n,dk]).  No max-subtraction: kh ~ N(0,1), exp <= ~300, safe.
__global__ __launch_bounds__(256)
void ctx_partial(const __hip_bfloat16* __restrict__ Kh,
                 const __hip_bfloat16* __restrict__ Vh,
                 float* __restrict__ Upart, float* __restrict__ Spart) {
  const int bh = blockIdx.y, chunk = blockIdx.x;
  const int b = bh / 12, h = bh % 12;
  const int t = threadIdx.x;
  const int rr = t >> 6, d = t & 63;
  const int tdk = (t & 15) * 4, tdv = (t >> 4) * 4;
  __shared__ float ek[4][64];
  __shared__ float vv[4][64];
  __shared__ float sred[256];
  f32x4 U[4] = {};
  float myS = 0.f;
  const long base = ((long)b * 4096 + (long)chunk * 512) * 768 + h * 64 + d;
  for (int r4 = 0; r4 < 128; ++r4) {
    const long off = base + (long)(r4 * 4 + rr) * 768;
    const float e = __expf(bf2f(Kh[off]));
    ek[rr][d] = e;
    myS += e;
    vv[rr][d] = bf2f(Vh[off]);
    __syncthreads();
#pragma unroll
    for (int q = 0; q < 4; ++q) {
      const f32x4 a = *(const f32x4*)&ek[q][tdk];
      const f32x4 vx = *(const f32x4*)&vv[q][tdv];
      U[0] += a[0] * vx;
      U[1] += a[1] * vx;
      U[2] += a[2] * vx;
      U[3] += a[3] * vx;
    }
    __syncthreads();
  }
  float* Ub = Upart + (long)(bh * 8 + chunk) * 4096;
#pragma unroll
  for (int i = 0; i < 4; ++i) *(f32x4*)&Ub[(tdk + i) * 64 + tdv] = U[i];
  sred[t] = myS;
  __syncthreads();
  if (t < 64) {
    const float s = sred[t] + sred[t + 64] + sred[t + 128] + sred[t + 192];
    Spart[(long)(bh * 8 + chunk) * 64 + t] = s;
  }
}

__global__ __launch_bounds__(256)
void ctx_reduce(const float* __restrict__ Upart, const float* __restrict__ Spart,
                float* __restrict__ ctx) {
  const int bh = blockIdx.x;
  const int t = threadIdx.x;
  const int tdk = (t & 15) * 4, tdv = (t >> 4) * 4;
  __shared__ float S[64];
  if (t < 64) {
    float s = 0.f;
#pragma unroll
    for (int c = 0; c < 8; ++c) s += Spart[(long)(bh * 8 + c) * 64 + t];
    S[t] = s;
  }
  __syncthreads();
#pragma unroll
  for (int i = 0; i < 4; ++i) {
    const int dk = tdk + i;
    f32x4 u = {};
#pragma unroll
    for (int c = 0; c < 8; ++c)
      u += *(const f32x4*)&Upart[(long)(bh * 8 + c) * 4096 + dk * 64 + tdv];
    u *= (1.f / S[dk]);
    *(f32x4*)&ctx[(long)bh * 4096 + dk * 64 + tdv] = u;
  }
}

// ---------------------------------------------------------------- G matrix
// Gt[b][co][h*64+dk] = sum_dv ctx[b,h,dk,dv] * Wp[co, h*64+dv]   (bf16 out)
__global__ void gstack(const float* __restrict__ ctx,
                       const __hip_bfloat16* __restrict__ Wpb,
                       __bf16* __restrict__ Gt) {
  const int co = blockIdx.x, b = blockIdx.y, l = threadIdx.x;  // l = dk
  for (int h = 0; h < 12; ++h) {
    const float* crow = ctx + ((long)(b * 12 + h) * 64 + l) * 64;
    const __hip_bfloat16* wrow = Wpb + (long)co * 768 + h * 64;
    float sum = 0.f;
    for (int dv = 0; dv < 64; dv += 4) {
      const f32x4 c4 = *(const f32x4*)&crow[dv];
      sum += c4[0] * bf2f(wrow[dv]) + c4[1] * bf2f(wrow[dv + 1]) +
             c4[2] * bf2f(wrow[dv + 2]) + c4[3] * bf2f(wrow[dv + 3]);
    }
    Gt[((long)b * 768 + co) * 768 + h * 64 + l] = (__bf16)sum;
  }
}

// ---------------------------------------------------------------- launch
extern "C" void kernel_launch(void* const* d_in, const int* in_sizes, int n_in,
                              void* d_out, int out_size, void* d_ws, size_t ws_size,
                              hipStream_t stream) {
  (void)in_sizes; (void)n_in; (void)out_size; (void)ws_size;
  const float* q = (const float*)d_in[0];
  const float* k = (const float*)d_in[1];
  const float* v = (const float*)d_in[2];
  const float* Wq = (const float*)d_in[3];
  const float* Wk = (const float*)d_in[4];
  const float* Wv = (const float*)d_in[5];
  const float* Wp = (const float*)d_in[6];
  const float* bp = (const float*)d_in[7];
  float* out = (float*)d_out;

  const long XE = 32768L * 768L;
  const long WE = 768L * 768L;

  // ws layout (~139 MB)
  char* ws = (char*)d_ws;
  __bf16* Khb = (__bf16*)ws;                             // XE bf16
  __bf16* Vhb = Khb + XE;                                // XE bf16
  __bf16* Wb = Vhb + XE;                                 // 4*WE bf16: Wk,Wv,Wp,WqT
  __bf16* Gt = Wb + 4 * WE;                              // 8*WE bf16
  __bf16* Mt = Gt + 8 * WE;                              // 8*WE bf16
  float* Upart = (float*)(Mt + 8 * WE);                  // 96*8*4096 f32
  float* Spart = Upart + 96L * 8 * 4096;                 // 96*8*64 f32
  float* ctx = Spart + 96L * 8 * 64;                     // 96*4096 f32

  // 1) weight casts (tiny)
  cast_kernel<<<576, 256, 0, stream>>>(Wk, Wb + 0 * WE, WE);
  cast_kernel<<<576, 256, 0, stream>>>(Wv, Wb + 1 * WE, WE);
  cast_kernel<<<576, 256, 0, stream>>>(Wp, Wb + 2 * WE, WE);
  transpose_cast<<<dim3(24, 24), dim3(32, 8), 0, stream>>>(Wq, Wb + 3 * WE);  // WqT

  // 2) K/V projections, fp32 A direct (fused cast):  Kh = k @ Wk^T, Vh = v @ Wv^T
  gemm_bt<true><<<dim3(6, 256, 1), 256, 0, stream>>>(k, Wb + 0 * WE, Khb, nullptr,
                                                     nullptr, 0, 0, 0, 0);
  gemm_bt<true><<<dim3(6, 256, 1), 256, 0, stream>>>(v, Wb + 1 * WE, Vhb, nullptr,
                                                     nullptr, 0, 0, 0, 0);

  // 3) softmax-weighted context
  ctx_partial<<<dim3(8, 96), 256, 0, stream>>>((const __hip_bfloat16*)Khb,
                                               (const __hip_bfloat16*)Vhb, Upart, Spart);
  ctx_reduce<<<96, 256, 0, stream>>>(Upart, Spart, ctx);

  // 4) Gt[b] = (ctx @ Wp-blocks)^T   (bf16, per batch)
  gstack<<<dim3(768, 8), 64, 0, stream>>>(ctx, (const __hip_bfloat16*)(Wb + 2 * WE), Gt);

  // 5) Mt[b] : out[m=co, n=ci] = sum_k Gt[co,k] * WqT[ci,k]
  gemm_bt<false><<<dim3(6, 6, 8), 256, 0, stream>>>(Gt, Wb + 3 * WE, Mt, nullptr,
                                                    nullptr, WE, 0, WE, 0);

  // 6) out[b] = q[b] @ Mt[b]^T + bp  (fp32 A direct, fp32 out)
  gemm_bt<true><<<dim3(6, 256, 1), 256, 0, stream>>>(q, Mt, nullptr, out,
                                                     bp, 0, 0, 0, WE);
}

// Round 4
// 378.437 us; speedup vs baseline: 1.5303x; 1.3436x over previous
//
#include <hip/hip_runtime.h>
#include <hip/hip_bf16.h>

// FactorAtt (CoaT) fused pipeline v3, MI355X/gfx950.
// B=8, N=4096, C=768, H=12, D=64.  M_tot = B*N = 32768.
//
// Math: out[b] = q[b] @ M[b] + bp, where
//   Kh = k @ Wk^T (bf16), Vh = v @ Wv^T
//   ctx[b,h,dk,dv] = sum_n softmax_n(Kh)[n,dk] * Vh[n,dv]
//   Gt[b][co][h*64+dk] = sum_dv ctx[b,h,dk,dv] * Wp[co, h*64+dv]
//   Mt[b][co][ci] = sum_kk Gt[b][co][kk] * Wq[kk][ci]      (= (Wq^T G)^T)
//   out[b][n,co] = sum_ci q[b][n,ci] * Mt[b][co,ci] + bp[co]
// v3: gstack rewritten (was 153us latency-bound w/ 64-thread blocks + scalar
// loads; now LDS-staged fp32 W + ctx-row-in-registers, ~10us).

typedef __bf16 bf16x8 __attribute__((ext_vector_type(8)));
typedef __bf16 bf16x4 __attribute__((ext_vector_type(4)));
typedef float f32x4 __attribute__((ext_vector_type(4)));

#define GLOAD_LDS16(g, l)                                                        \
  __builtin_amdgcn_global_load_lds(                                              \
      (const __attribute__((address_space(1))) void*)(g),                        \
      (__attribute__((address_space(3))) void*)(l), 16, 0, 0)

__device__ __forceinline__ float bf2f(__hip_bfloat16 h) { return __bfloat162float(h); }

// ---------------------------------------------------------------- cast fp32->bf16
__global__ void cast_kernel(const float* __restrict__ src,
                            __bf16* __restrict__ dst, long n) {
  long i = ((long)blockIdx.x * blockDim.x + threadIdx.x) * 4;
  if (i + 3 < n) {
    const float4 f = *(const float4*)(src + i);
    bf16x4 u = {(__bf16)f.x, (__bf16)f.y, (__bf16)f.z, (__bf16)f.w};
    *(bf16x4*)(dst + i) = u;
  }
}

// ---------------------------------------------------------------- transpose cast
// dst[ci][kk] = src[kk][ci]  (768x768, fp32 -> bf16)
__global__ void transpose_cast(const float* __restrict__ src,
                               __bf16* __restrict__ dst) {
  __shared__ float tile[32][33];
  const int bx = blockIdx.x * 32, by = blockIdx.y * 32;  // bx: kk base, by: ci base
  const int tx = threadIdx.x, ty = threadIdx.y;          // 32 x 8
#pragma unroll
  for (int j = 0; j < 32; j += 8)
    tile[ty + j][tx] = src[(long)(bx + ty + j) * 768 + by + tx];
  __syncthreads();
#pragma unroll
  for (int j = 0; j < 32; j += 8)
    dst[(long)(by + ty + j) * 768 + bx + tx] = (__bf16)tile[tx][ty + j];
}

// ---------------------------------------------------------------- GEMM (B^T form)
// out[m,n] = sum_k A[m,k] * Bt[n,k];  K=768 fixed, tiles 128x128, BK=32, 4 waves.
// AF32: A is fp32 in global, cast to bf16 at LDS->frag read (XOR-swizzled LDS).
// z-batched: A += z*sAz, Bt += z*sBz, outB += z*sOz.  If outF: fp32 out + bias,
// Bt additionally batched per 4096 rows (sBbatch).
template <bool AF32>
__global__ __launch_bounds__(256, 2)
void gemm_bt(const void* __restrict__ Abase_,
             const __bf16* __restrict__ Btbase,
             __bf16* __restrict__ outBbase,
             float* __restrict__ outF,
             const float* __restrict__ bias,
             long sAz, long sBz, long sOz, long sBbatch) {
  constexpr int K = 768;
  const int tid = threadIdx.x;
  const int lane = tid & 63;
  const int w = tid >> 6;
  const int wr = (w >> 1) * 64;
  const int wc = (w & 1) * 64;

  // bijective XCD-chunked swizzle (m204)
  long flat = ((long)blockIdx.z * gridDim.y + blockIdx.y) * gridDim.x + blockIdx.x;
  const long total = (long)gridDim.x * gridDim.y * gridDim.z;
  if ((total & 7) == 0) {
    flat = (flat & 7) * (total >> 3) + (flat >> 3);
  }
  const int bx = (int)(flat % gridDim.x);
  const long rem = flat / gridDim.x;
  const int by = (int)(rem % gridDim.y);
  const int bz = (int)(rem / gridDim.y);

  const int z = bz;
  const int m0 = by * 128;
  const int n0 = bx * 128;

  const __bf16* Bt = Btbase + (long)z * sBz + (long)(m0 >> 12) * sBbatch;

  __shared__ __align__(16) float AsF[AF32 ? 128 * 32 : 8];
  __shared__ __align__(16) __bf16 AsB[AF32 ? 8 : 128 * 32];
  __shared__ __align__(16) __bf16 Bs[128 * 32];

  f32x4 acc[4][4] = {};

  // B (bf16): wave w covers rows w*16..+15 (and +64); lane: row = lane>>2, chunk = lane&3
  const int srow = w * 16 + (lane >> 2);
  const int scol = (lane & 3) * 8;
  const __bf16* gB = Bt + (long)(n0 + srow) * K + scol;
  __bf16* lB = &Bs[(w * 16) * 32];

  // A fp32: per issue p (0..3), rows p*32 + w*8 + (lane>>3), chunk lane&7 (16B units)
  // XOR swizzle: physical chunk c holds logical chunk c ^ (row&7)
  const int sr8 = lane >> 3;
  const int c_log = (lane & 7) ^ sr8;
  const float* gAf = nullptr;
  float* lAf = nullptr;
  const __bf16* gAb = nullptr;
  __bf16* lAb = nullptr;
  if (AF32) {
    const float* Af = (const float*)Abase_ + (long)z * sAz;
    gAf = Af + (long)(m0 + w * 8 + sr8) * K + c_log * 4;
    lAf = &AsF[(w * 8) * 32];
  } else {
    const __bf16* Ab = (const __bf16*)Abase_ + (long)z * sAz;
    gAb = Ab + (long)(m0 + srow) * K + scol;
    lAb = &AsB[(w * 16) * 32];
  }

  const int kseg = (lane >> 4) * 8;
  const int rsel = lane & 15;
  const int r7 = rsel & 7;

  for (int k0 = 0; k0 < K; k0 += 32) {
    if (AF32) {
#pragma unroll
      for (int p = 0; p < 4; ++p)
        GLOAD_LDS16(gAf + k0 + (long)p * 32 * K, lAf + p * 32 * 32);
    } else {
      GLOAD_LDS16(gAb + k0, lAb);
      GLOAD_LDS16(gAb + (long)64 * K + k0, lAb + 64 * 32);
    }
    GLOAD_LDS16(gB + k0, lB);
    GLOAD_LDS16(gB + (long)64 * K + k0, lB + 64 * 32);
    __syncthreads();

    bf16x8 af[4], bfr[4];
#pragma unroll
    for (int i = 0; i < 4; ++i) {
      const int row = wr + i * 16 + rsel;
      if (AF32) {
        const int c0 = kseg >> 2;
        const f32x4 lo = *(const f32x4*)&AsF[row * 32 + ((c0 ^ r7) << 2)];
        const f32x4 hi = *(const f32x4*)&AsF[row * 32 + (((c0 + 1) ^ r7) << 2)];
        bf16x8 a = {(__bf16)lo[0], (__bf16)lo[1], (__bf16)lo[2], (__bf16)lo[3],
                    (__bf16)hi[0], (__bf16)hi[1], (__bf16)hi[2], (__bf16)hi[3]};
        af[i] = a;
      } else {
        af[i] = *(const bf16x8*)&AsB[row * 32 + kseg];
      }
      bfr[i] = *(const bf16x8*)&Bs[(wc + i * 16 + rsel) * 32 + kseg];
    }
#pragma unroll
    for (int i = 0; i < 4; ++i)
#pragma unroll
      for (int j = 0; j < 4; ++j)
        acc[i][j] = __builtin_amdgcn_mfma_f32_16x16x32_bf16(af[i], bfr[j], acc[i][j], 0, 0, 0);
    __syncthreads();
  }

  // C/D layout (m89): col = lane&15, row = (lane>>4)*4 + r
  const int r0 = (lane >> 4) * 4;
  if (outF == nullptr) {
    __bf16* outp = outBbase + (long)z * sOz;
#pragma unroll
    for (int i = 0; i < 4; ++i) {
      const int row = m0 + wr + i * 16 + r0;
#pragma unroll
      for (int j = 0; j < 4; ++j) {
        const int col = n0 + wc + j * 16 + rsel;
#pragma unroll
        for (int r = 0; r < 4; ++r)
          outp[(long)(row + r) * 768 + col] = (__bf16)acc[i][j][r];
      }
    }
  } else {
#pragma unroll
    for (int i = 0; i < 4; ++i) {
      const int row = m0 + wr + i * 16 + r0;
#pragma unroll
      for (int j = 0; j < 4; ++j) {
        const int col = n0 + wc + j * 16 + rsel;
        const float bv = bias[col];
#pragma unroll
        for (int r = 0; r < 4; ++r)
          outF[(long)(row + r) * 768 + col] = acc[i][j][r] + bv;
      }
    }
  }
}

// ---------------------------------------------------------------- ctx partials
__global__ __launch_bounds__(256)
void ctx_partial(const __hip_bfloat16* __restrict__ Kh,
                 const __hip_bfloat16* __restrict__ Vh,
                 float* __restrict__ Upart, float* __restrict__ Spart) {
  const int bh = blockIdx.y, chunk = blockIdx.x;
  const int b = bh / 12, h = bh % 12;
  const int t = threadIdx.x;
  const int rr = t >> 6, d = t & 63;
  const int tdk = (t & 15) * 4, tdv = (t >> 4) * 4;
  __shared__ float ek[4][64];
  __shared__ float vv[4][64];
  __shared__ float sred[256];
  f32x4 U[4] = {};
  float myS = 0.f;
  const long base = ((long)b * 4096 + (long)chunk * 512) * 768 + h * 64 + d;
  for (int r4 = 0; r4 < 128; ++r4) {
    const long off = base + (long)(r4 * 4 + rr) * 768;
    const float e = __expf(bf2f(Kh[off]));
    ek[rr][d] = e;
    myS += e;
    vv[rr][d] = bf2f(Vh[off]);
    __syncthreads();
#pragma unroll
    for (int q = 0; q < 4; ++q) {
      const f32x4 a = *(const f32x4*)&ek[q][tdk];
      const f32x4 vx = *(const f32x4*)&vv[q][tdv];
      U[0] += a[0] * vx;
      U[1] += a[1] * vx;
      U[2] += a[2] * vx;
      U[3] += a[3] * vx;
    }
    __syncthreads();
  }
  float* Ub = Upart + (long)(bh * 8 + chunk) * 4096;
#pragma unroll
  for (int i = 0; i < 4; ++i) *(f32x4*)&Ub[(tdk + i) * 64 + tdv] = U[i];
  sred[t] = myS;
  __syncthreads();
  if (t < 64) {
    const float s = sred[t] + sred[t + 64] + sred[t + 128] + sred[t + 192];
    Spart[(long)(bh * 8 + chunk) * 64 + t] = s;
  }
}

__global__ __launch_bounds__(256)
void ctx_reduce(const float* __restrict__ Upart, const float* __restrict__ Spart,
                float* __restrict__ ctx) {
  const int bh = blockIdx.x;
  const int t = threadIdx.x;
  const int tdk = (t & 15) * 4, tdv = (t >> 4) * 4;
  __shared__ float S[64];
  if (t < 64) {
    float s = 0.f;
#pragma unroll
    for (int c = 0; c < 8; ++c) s += Spart[(long)(bh * 8 + c) * 64 + t];
    S[t] = s;
  }
  __syncthreads();
#pragma unroll
  for (int i = 0; i < 4; ++i) {
    const int dk = tdk + i;
    f32x4 u = {};
#pragma unroll
    for (int c = 0; c < 8; ++c)
      u += *(const f32x4*)&Upart[(long)(bh * 8 + c) * 4096 + dk * 64 + tdv];
    u *= (1.f / S[dk]);
    *(f32x4*)&ctx[(long)bh * 4096 + dk * 64 + tdv] = u;
  }
}

// ---------------------------------------------------------------- G matrix (v3)
// Gt[b][co][h*64+dk] = sum_dv ctx[b,h,dk,dv] * Wp[co, h*64+dv]   (bf16 out)
// grid (co-chunk=4, h=12, b=8), 256 threads (4 waves).  lane = dk.
// Wp chunk [192co][64dv] staged fp32 in LDS (48KB); ctx row in 16 f32x4 regs.
// Inner loop per co: 16 wave-uniform (broadcast) ds_read_b128 + 64 FMA.
__global__ __launch_bounds__(256, 2)
void gstack(const float* __restrict__ ctx, const float* __restrict__ Wp,
            __bf16* __restrict__ Gt) {
  const int cc = blockIdx.x, h = blockIdx.y, b = blockIdx.z;
  const int t = threadIdx.x, lane = t & 63, w = t >> 6;
  const int co0 = cc * 192;
  __shared__ __align__(16) float wf[192 * 64];  // 48 KB

  // stage Wp[co0+r][h*64 + c] -> wf[r*64 + c]  (fp32, coalesced 16B loads)
#pragma unroll
  for (int i = 0; i < 12; ++i) {
    const int flat = i * 256 + t;        // 0..3071 vec4 slots
    const int r = flat >> 4, c4 = flat & 15;
    const f32x4 vsrc = *(const f32x4*)&Wp[(long)(co0 + r) * 768 + h * 64 + c4 * 4];
    *(f32x4*)&wf[r * 64 + c4 * 4] = vsrc;
  }

  // ctx row for this lane: ctx[b,h,dk=lane, 0..63]
  f32x4 cx[16];
  const float* crow = ctx + ((long)(b * 12 + h) * 64 + lane) * 64;
#pragma unroll
  for (int j = 0; j < 16; ++j) cx[j] = *(const f32x4*)&crow[j * 4];

  __syncthreads();

  __bf16* gout = Gt + ((long)(b * 768 + co0 + w * 48) * 768) + h * 64 + lane;
  for (int co = 0; co < 48; ++co) {
    const float* wrow = &wf[(w * 48 + co) * 64];
    f32x4 acc = {};
#pragma unroll
    for (int j = 0; j < 16; ++j) acc += cx[j] * *(const f32x4*)&wrow[j * 4];
    const float s = acc[0] + acc[1] + acc[2] + acc[3];
    gout[(long)co * 768] = (__bf16)s;
  }
}

// ---------------------------------------------------------------- launch
extern "C" void kernel_launch(void* const* d_in, const int* in_sizes, int n_in,
                              void* d_out, int out_size, void* d_ws, size_t ws_size,
                              hipStream_t stream) {
  (void)in_sizes; (void)n_in; (void)out_size; (void)ws_size;
  const float* q = (const float*)d_in[0];
  const float* k = (const float*)d_in[1];
  const float* v = (const float*)d_in[2];
  const float* Wq = (const float*)d_in[3];
  const float* Wk = (const float*)d_in[4];
  const float* Wv = (const float*)d_in[5];
  const float* Wp = (const float*)d_in[6];
  const float* bp = (const float*)d_in[7];
  float* out = (float*)d_out;

  const long XE = 32768L * 768L;
  const long WE = 768L * 768L;

  // ws layout (~139 MB)
  char* ws = (char*)d_ws;
  __bf16* Khb = (__bf16*)ws;                             // XE bf16
  __bf16* Vhb = Khb + XE;                                // XE bf16
  __bf16* Wb = Vhb + XE;                                 // 4*WE bf16: Wk,Wv,(unused),WqT
  __bf16* Gt = Wb + 4 * WE;                              // 8*WE bf16
  __bf16* Mt = Gt + 8 * WE;                              // 8*WE bf16
  float* Upart = (float*)(Mt + 8 * WE);                  // 96*8*4096 f32
  float* Spart = Upart + 96L * 8 * 4096;                 // 96*8*64 f32
  float* ctx = Spart + 96L * 8 * 64;                     // 96*4096 f32

  // 1) weight casts (tiny)
  cast_kernel<<<576, 256, 0, stream>>>(Wk, Wb + 0 * WE, WE);
  cast_kernel<<<576, 256, 0, stream>>>(Wv, Wb + 1 * WE, WE);
  transpose_cast<<<dim3(24, 24), dim3(32, 8), 0, stream>>>(Wq, Wb + 3 * WE);  // WqT

  // 2) K/V projections, fp32 A direct (fused cast)
  gemm_bt<true><<<dim3(6, 256, 1), 256, 0, stream>>>(k, Wb + 0 * WE, Khb, nullptr,
                                                     nullptr, 0, 0, 0, 0);
  gemm_bt<true><<<dim3(6, 256, 1), 256, 0, stream>>>(v, Wb + 1 * WE, Vhb, nullptr,
                                                     nullptr, 0, 0, 0, 0);

  // 3) softmax-weighted context
  ctx_partial<<<dim3(8, 96), 256, 0, stream>>>((const __hip_bfloat16*)Khb,
                                               (const __hip_bfloat16*)Vhb, Upart, Spart);
  ctx_reduce<<<96, 256, 0, stream>>>(Upart, Spart, ctx);

  // 4) Gt[b] = (ctx @ Wp-blocks)^T   (bf16, per batch; fp32 Wp direct)
  gstack<<<dim3(4, 12, 8), 256, 0, stream>>>(ctx, Wp, Gt);

  // 5) Mt[b] : out[m=co, n=ci] = sum_k Gt[co,k] * WqT[ci,k]
  gemm_bt<false><<<dim3(6, 6, 8), 256, 0, stream>>>(Gt, Wb + 3 * WE, Mt, nullptr,
                                                    nullptr, WE, 0, WE, 0);

  // 6) out[b] = q[b] @ Mt[b]^T + bp  (fp32 A direct, fp32 out)
  gemm_bt<true><<<dim3(6, 256, 1), 256, 0, stream>>>(q, Mt, nullptr, out,
                                                     bp, 0, 0, 0, WE);
}